// Round 4
// baseline (606.607 us; speedup 1.0000x reference)
//
#include <hip/hip_runtime.h>
#include <hip/hip_bf16.h>
#include <stdint.h>

// Problem constants
#define N_NODES 8192
#define N_EDGES 16384
#define N_GRAPHS 512
#define IN_DIM 235
#define H_DIM 64
#define ED_DIM 52
#define HID1 128          // edge-MLP hidden width (W1 rows)
#define KP 256            // K padded 235 -> 256 for MFMA tiling
#define NB 3328           // H_DIM * ED_DIM = P column count

// P column layout: c = (d>>2)*256 + h*4 + (d&3)  [d4-major, h-interleaved]

// prep job partition
#define BT_BLOCKS 940     // 235 i x 4 h-groups
#define EXT_BLOCKS 128
#define ZERO_BLOCKS 16
#define A_BLOCKS 1024
#define PREP_JOBS (BT_BLOCKS + EXT_BLOCKS + ZERO_BLOCKS + A_BLOCKS)  // 2108

#define GEMM_JOBS 1728    // 64 m-tiles x 27 n-tiles
#define GRID 768          // = 256 CU x 3 blocks/CU, co-resident by construction
                          // (LDS 36352*3 <= 160K, launch_bounds(256,3) pins VGPR)

typedef __bf16 bf16x8 __attribute__((ext_vector_type(8)));
typedef float f32x4 __attribute__((ext_vector_type(4)));

static __device__ inline unsigned short f2bf(float f) {
    union { float f; unsigned u; } v; v.f = f;
    unsigned r = v.u + 0x7FFFu + ((v.u >> 16) & 1u);   // RNE
    return (unsigned short)(r >> 16);
}

struct MegaArgs {
    const float* x; const int* ei; const float* ea; const int* batch;
    const float* W1; const float* b1; const float* W2; const float* b2;
    const float* root; const float* conv_b;
    const float* fw1; const float* fb1; const float* fw2; const float* fb2;
    const float* fw3; const float* fb3; const float* fw4; const float* fb4;
    float* out;
    unsigned short* A; unsigned short* Bt; unsigned short* P;
    float* agg; float* xb2;
    unsigned* bar;        // 3 single-use counters, 128B apart, memset to 0
};

// Software grid barrier, v2. R3 proved the protocol correct but polled with
// atomicAdd(ctr,0) -- a device-scope RMW. 576 pollers x serialized RMW on one
// line backlogged the coherence point (~85us/barrier, measured). Fix: poll
// with a device-scope atomic LOAD (coherent, non-serializing) + s_sleep
// backoff. Arrival is unchanged (threadfence release + atomicAdd, R3-proven).
static __device__ inline void grid_barrier(unsigned* ctr, unsigned nb) {
    __syncthreads();
    if (threadIdx.x == 0) {
        __threadfence();                      // agent release: flush my writes
        atomicAdd(ctr, 1u);
        unsigned spins = 0;
        while (__hip_atomic_load(ctr, __ATOMIC_ACQUIRE,
                                 __HIP_MEMORY_SCOPE_AGENT) < nb) {
            __builtin_amdgcn_s_sleep(16);     // ~1k cycles between polls
            if (++spins > 500000u) break;     // escape hatch: no hang, ever
        }
        __threadfence();                      // agent acquire: invalidate stale
    }
    __syncthreads();
}

// ---------------------------------------------------------------------------
// Single fused kernel: prep -> gemm -> edge -> tail, software grid barriers.
// Phase bodies identical to the passing R1/R3 versions.
__global__ __launch_bounds__(256, 3) void k_mega(MegaArgs a) {
    __shared__ __align__(16) char smem[35904];
    const int bid = blockIdx.x;
    const int t = threadIdx.x;

    // ================= PHASE 0: prep (A, Bt build) =================
    {
        float* w1s = (float*)smem;                       // [52][132]
        float* w2s = (float*)(smem + ED_DIM * 132 * 4);  // [16][132]
        // W1 stage is job-invariant: load once. BT jobs are the lowest job
        // ids a block sees, and ext/zero/A jobs never touch LDS, so w1s
        // survives until the phase barrier. First per-job __syncthreads
        // publishes it before first use.
        for (int j = t; j < ED_DIM * HID1; j += 256) {
            const int k = j / ED_DIM, d = j - k * ED_DIM;
            w1s[d * 132 + k] = a.W1[j];
        }
        for (int job = bid; job < PREP_JOBS; job += GRID) {
            if (job < BT_BLOCKS) {
                // Bt compose: C[i][(h,d)] = sum_k W2[(i*64+h)*128+k]*W1[k*52+d]
                const int i = job >> 2;               // 0..234
                const int by = job & 3;               // h base by*16
                __syncthreads();                      // w1s visible / prior job done
                const float* w2src = a.W2 + ((size_t)i * 64 + by * 16) * HID1;
                for (int j = t; j < 16 * HID1; j += 256)
                    w2s[(j >> 7) * 132 + (j & 127)] = w2src[j];
                __syncthreads();
                const int hh = t & 15, dq = t >> 4;
                const int h = by * 16 + hh;
                const float4* w2v = (const float4*)&w2s[hh * 132];
                #pragma unroll
                for (int m = 0; m < 4; ++m) {
                    const int d = dq + m * 16;
                    if (d >= ED_DIM) break;
                    const float4* w1v = (const float4*)&w1s[d * 132];
                    float acc = 0.f;
                    #pragma unroll
                    for (int k4 = 0; k4 < HID1 / 4; ++k4) {
                        const float4 u = w1v[k4], v = w2v[k4];
                        acc += u.x * v.x + u.y * v.y + u.z * v.z + u.w * v.w;
                    }
                    const int p = ((d >> 2) << 8) + h * 4 + (d & 3);
                    a.Bt[(size_t)p * KP + i] = f2bf(acc);
                }
            } else if (job < BT_BLOCKS + EXT_BLOCKS) {
                // ext cols: 3328+j (j<64) = root[:,j]; 3392+j = bc[:,j-64]
                const int j = job - BT_BLOCKS;        // 0..127
                const int i = t;                      // 0..255
                if (i < IN_DIM) {
                    float v;
                    if (j < 64) {
                        v = a.root[i * H_DIM + j];
                    } else {
                        const int jj = i * H_DIM + (j - 64);
                        float acc = a.b2[jj];
                        const float4* w = (const float4*)(a.W2 + (size_t)jj * HID1);
                        const float4* bv = (const float4*)a.b1;
                        #pragma unroll
                        for (int k4 = 0; k4 < HID1 / 4; ++k4) {
                            const float4 u = w[k4], b4 = bv[k4];
                            acc += u.x * b4.x; acc += u.y * b4.y;
                            acc += u.z * b4.z; acc += u.w * b4.w;
                        }
                        v = acc;
                    }
                    a.Bt[(size_t)(NB + j) * KP + i] = f2bf(v);
                }
            } else if (job < BT_BLOCKS + EXT_BLOCKS + ZERO_BLOCKS) {
                // Bt pad-col zeroing: rows 0..3455, cols 235..255
                const int z = job - BT_BLOCKS - EXT_BLOCKS;
                const int TOT = 3456 * 21;
                for (int idx = z * 256 + t; idx < TOT; idx += ZERO_BLOCKS * 256) {
                    const int r = idx / 21, c = IN_DIM + idx - r * 21;
                    a.Bt[(size_t)r * KP + c] = 0;
                }
            } else {
                // A build: x (fp32) -> A (bf16 [8192,256], cols >=235 zero)
                const int j8 = (job - BT_BLOCKS - EXT_BLOCKS - ZERO_BLOCKS) * 256 + t;
                const int n = j8 >> 5, i0 = (j8 & 31) * 8;
                const float* xr = a.x + (size_t)n * IN_DIM;
                union { unsigned short us[8]; uint4 qv; } pk;
                #pragma unroll
                for (int k = 0; k < 8; ++k) {
                    const int i = i0 + k;
                    pk.us[k] = (i < IN_DIM) ? f2bf(xr[i]) : (unsigned short)0;
                }
                *(uint4*)(&a.A[(size_t)j8 * 8]) = pk.qv;
            }
        }
    }
    grid_barrier(&a.bar[0], GRID);

    // ================= PHASE 1: GEMM [8192,256]x[256,3456] =================
    // 128x128 tile / BK=32 / 4 waves, each 64x64 (4x4 MFMA). <=3 jobs/block.
    // XCD parity preserved (stride 768 % 8 == 0).
    {
        unsigned short* As = (unsigned short*)smem;   // 2*128*32 shorts = 16 KB
        unsigned short* Bs = As + 8192;               // 16 KB
        const int wid = t >> 6, lane = t & 63;
        const int wm = wid & 1;          // 64-row half
        const int wn = wid >> 1;         // 64-col half
        const int q = lane >> 4, r16 = lane & 15;
        const int pcq = (q ^ ((r16 >> 1) & 3)) * 8;   // physical chunk for logical q

        for (int job = bid; job < GEMM_JOBS; job += GRID) {
            const int xcd = job & 7, bi = job >> 3;
            const int mt = (bi / 27) * 8 + xcd;       // 0..63
            const int nt = bi % 27;                   // 0..26
            const int m0 = mt * 128, n0 = nt * 128;

            f32x4 acc[4][4] = {};

            auto stage = [&](int k0, int buf) {
                #pragma unroll
                for (int s2i = 0; s2i < 2; ++s2i) {
                    const int idx = s2i * 256 + t;    // 0..511, one 16B slot each
                    const int row = idx >> 2;         // 0..127
                    const int lgrp = ((idx & 3) ^ ((row >> 1) & 3)) * 8;
                    const unsigned short* ga = &a.A[(size_t)(m0 + row) * KP + k0 + lgrp];
                    const unsigned short* gb = &a.Bt[(size_t)(n0 + row) * KP + k0 + lgrp];
                    char* la = (char*)As + buf * 8192 + s2i * 4096 + wid * 1024;
                    char* lb = (char*)Bs + buf * 8192 + s2i * 4096 + wid * 1024;
                    __builtin_amdgcn_global_load_lds(
                        (const __attribute__((address_space(1))) unsigned int*)ga,
                        (__attribute__((address_space(3))) unsigned int*)la, 16, 0, 0);
                    __builtin_amdgcn_global_load_lds(
                        (const __attribute__((address_space(1))) unsigned int*)gb,
                        (__attribute__((address_space(3))) unsigned int*)lb, 16, 0, 0);
                }
            };

            stage(0, 0);   // prior job's buf0 reads are behind its it=7 barrier
            #pragma unroll
            for (int it = 0; it < 8; ++it) {
                __syncthreads();                      // drains prefetch for buf[it&1]
                if (it < 7) stage((it + 1) * 32, (it + 1) & 1);
                const int bo = (it & 1) * 4096;       // buffer offset in shorts
                bf16x8 af[4], bfr[4];
                #pragma unroll
                for (int mi = 0; mi < 4; ++mi)
                    af[mi] = *(const bf16x8*)(&As[bo + (wm * 64 + mi * 16 + r16) * 32 + pcq]);
                #pragma unroll
                for (int ni = 0; ni < 4; ++ni)
                    bfr[ni] = *(const bf16x8*)(&Bs[bo + (wn * 64 + ni * 16 + r16) * 32 + pcq]);
                #pragma unroll
                for (int mi = 0; mi < 4; ++mi)
                    #pragma unroll
                    for (int ni = 0; ni < 4; ++ni)
                        acc[mi][ni] = __builtin_amdgcn_mfma_f32_16x16x32_bf16(
                            bfr[ni], af[mi], acc[mi][ni], 0, 0, 0);   // transposed D
            }

            // Transposed D: lane (q,r16) holds rows m=mi*16+r16, cols n=ni*16+q*4..+3
            if (nt < 26) {
                #pragma unroll
                for (int mi = 0; mi < 4; ++mi)
                    #pragma unroll
                    for (int ni = 0; ni < 4; ++ni) {
                        const int row = m0 + wm * 64 + mi * 16 + r16;
                        const int col = n0 + wn * 64 + ni * 16 + q * 4;
                        union { unsigned short us[4]; uint2 u2; } pk;
                        #pragma unroll
                        for (int rr = 0; rr < 4; ++rr) pk.us[rr] = f2bf(acc[mi][ni][rr]);
                        *(uint2*)(&a.P[(size_t)row * NB + col]) = pk.u2;
                    }
            } else {
                // ext tile: cl<64 -> agg(+conv_b), else xb2
                #pragma unroll
                for (int mi = 0; mi < 4; ++mi)
                    #pragma unroll
                    for (int ni = 0; ni < 4; ++ni) {
                        const int row = m0 + wm * 64 + mi * 16 + r16;
                        const int cl = ni * 16 + q * 4;   // 0..63 within the half
                        if (wn == 0) {
                            const float4 cb = *(const float4*)&a.conv_b[cl];
                            float4 v;
                            v.x = acc[mi][ni][0] + cb.x; v.y = acc[mi][ni][1] + cb.y;
                            v.z = acc[mi][ni][2] + cb.z; v.w = acc[mi][ni][3] + cb.w;
                            *(float4*)(&a.agg[row * H_DIM + cl]) = v;
                        } else {
                            float4 v;
                            v.x = acc[mi][ni][0]; v.y = acc[mi][ni][1];
                            v.z = acc[mi][ni][2]; v.w = acc[mi][ni][3];
                            *(float4*)(&a.xb2[row * H_DIM + cl]) = v;
                        }
                    }
            }
        }
    }
    grid_barrier(&a.bar[32], GRID);

    // ================= PHASE 2: edge contraction =================
    // Per edge one wave, lane = h. d4-major P: 13 contiguous uint2 loads.
    for (int eb = bid; eb < N_EDGES / 4; eb += GRID) {
        const int e = eb * 4 + (t >> 6);
        const int h = t & 63;
        const int s = a.ei[e], dst = a.ei[N_EDGES + e];
        const uint2* Pr = (const uint2*)(a.P + (size_t)s * NB);
        const float4* ev = (const float4*)(a.ea + (size_t)e * ED_DIM);

        uint2 pv[13];
        #pragma unroll
        for (int j = 0; j < 13; ++j) pv[j] = Pr[j * 64 + h];
        float4 eav[13];
        #pragma unroll
        for (int j = 0; j < 13; ++j) eav[j] = ev[j];

        float acc = a.xb2[s * H_DIM + h];
        #pragma unroll
        for (int j = 0; j < 13; ++j) {
            union { unsigned u; float f; } a0, a1, b0, b1;
            a0.u = pv[j].x << 16; a1.u = pv[j].x & 0xffff0000u;
            b0.u = pv[j].y << 16; b1.u = pv[j].y & 0xffff0000u;
            acc += eav[j].x * a0.f + eav[j].y * a1.f
                 + eav[j].z * b0.f + eav[j].w * b1.f;
        }
        atomicAdd(&a.agg[dst * H_DIM + h], acc);
    }
    grid_barrier(&a.bar[64], GRID);

    // ================= PHASE 3: relu + mean-pool + MLP head =================
    for (int gid = bid; gid < N_GRAPHS; gid += GRID) {
        float* red = (float*)smem;        // 256
        float* sp  = red + 256;           // 64
        float* s1  = sp + 64;             // 128
        float* s2  = s1 + 128;            // 256
        float* s3  = s2 + 256;            // 128

        int lo = 0, hi = N_NODES;
        while (lo < hi) { const int mid = (lo + hi) >> 1; if (a.batch[mid] < gid) lo = mid + 1; else hi = mid; }
        const int start = lo;
        hi = N_NODES;
        while (lo < hi) { const int mid = (lo + hi) >> 1; if (a.batch[mid] <= gid) lo = mid + 1; else hi = mid; }
        const int end = lo;
        const float inv = 1.0f / fmaxf((float)(end - start), 1.0f);

        float acc0 = 0.f;
        for (int n = start + (t >> 6); n < end; n += 4)
            acc0 += fmaxf(a.agg[n * H_DIM + (t & 63)], 0.f);
        red[t] = acc0;
        __syncthreads();
        if (t < 64) sp[t] = (red[t] + red[t + 64] + red[t + 128] + red[t + 192]) * inv;
        __syncthreads();

        if (t < 128) {
            float acc = a.fb1[t];
            const float4* w = (const float4*)(a.fw1 + t * 64);
            const float4* sv = (const float4*)sp;
            #pragma unroll
            for (int k = 0; k < 16; ++k) {
                const float4 u = w[k], b4 = sv[k];
                acc += u.x * b4.x; acc += u.y * b4.y; acc += u.z * b4.z; acc += u.w * b4.w;
            }
            s1[t] = fmaxf(acc, 0.f);
        }
        __syncthreads();
        {
            float acc = a.fb2[t];
            const float4* w = (const float4*)(a.fw2 + t * 128);
            const float4* sv = (const float4*)s1;
            #pragma unroll
            for (int k = 0; k < 32; ++k) {
                const float4 u = w[k], b4 = sv[k];
                acc += u.x * b4.x; acc += u.y * b4.y; acc += u.z * b4.z; acc += u.w * b4.w;
            }
            s2[t] = fmaxf(acc, 0.f);
        }
        __syncthreads();
        if (t < 128) {
            float acc = a.fb3[t];
            const float4* w = (const float4*)(a.fw3 + t * 256);
            const float4* sv = (const float4*)s2;
            #pragma unroll
            for (int k = 0; k < 64; ++k) {
                const float4 u = w[k], b4 = sv[k];
                acc += u.x * b4.x; acc += u.y * b4.y; acc += u.z * b4.z; acc += u.w * b4.w;
            }
            s3[t] = fmaxf(acc, 0.f);
        }
        __syncthreads();
        if (t < 64) {
            float p = s3[t] * a.fw4[t] + s3[t + 64] * a.fw4[t + 64];
            #pragma unroll
            for (int off = 32; off > 0; off >>= 1) p += __shfl_down(p, off);
            if (t == 0) a.out[gid] = p + a.fb4[0];
        }
        __syncthreads();   // protect LDS before a possible next gid iteration
    }
}

// ---------------------------------------------------------------------------
extern "C" void kernel_launch(void* const* d_in, const int* in_sizes, int n_in,
                              void* d_out, int out_size, void* d_ws, size_t ws_size,
                              hipStream_t stream) {
    char* ws = (char*)d_ws;
    // workspace layout (16B-aligned), total ~64.8 MB + barrier page
    unsigned short* A   = (unsigned short*)(ws);             // 8192*256*2   = 4,194,304
    unsigned short* Bt  = (unsigned short*)(ws + 4194304);   // 3584*256*2   = 1,835,008
    unsigned short* P   = (unsigned short*)(ws + 6029312);   // 8192*3328*2  = 54,525,952
    float* agg  = (float*)(ws + 60555264);                   // 8192*64*4    = 2,097,152
    float* xb2  = (float*)(ws + 62652416);                   // 8192*64*4    = 2,097,152
    unsigned* bar = (unsigned*)(ws + 64749568);              // 3 counters, 128B apart

    MegaArgs ma;
    ma.x      = (const float*)d_in[0];
    ma.ei     = (const int*)d_in[1];
    ma.ea     = (const float*)d_in[2];
    ma.batch  = (const int*)d_in[3];
    ma.W1     = (const float*)d_in[4];
    ma.b1     = (const float*)d_in[5];
    ma.W2     = (const float*)d_in[6];
    ma.b2     = (const float*)d_in[7];
    ma.root   = (const float*)d_in[8];
    ma.conv_b = (const float*)d_in[9];
    ma.fw1 = (const float*)d_in[10]; ma.fb1 = (const float*)d_in[11];
    ma.fw2 = (const float*)d_in[12]; ma.fb2 = (const float*)d_in[13];
    ma.fw3 = (const float*)d_in[14]; ma.fb3 = (const float*)d_in[15];
    ma.fw4 = (const float*)d_in[16]; ma.fb4 = (const float*)d_in[17];
    ma.out = (float*)d_out;
    ma.A = A; ma.Bt = Bt; ma.P = P; ma.agg = agg; ma.xb2 = xb2;
    ma.bar = bar;

    hipMemsetAsync(bar, 0, 384, stream);   // zero the 3 barrier counters
    k_mega<<<dim3(GRID), dim3(256), 0, stream>>>(ma);
}

// Round 5
// 183.614 us; speedup vs baseline: 3.3037x; 3.3037x over previous
//
#include <hip/hip_runtime.h>
#include <hip/hip_bf16.h>
#include <stdint.h>

// Problem constants
#define N_NODES 8192
#define N_EDGES 16384
#define N_GRAPHS 512
#define IN_DIM 235
#define H_DIM 64
#define ED_DIM 52
#define HID1 128          // edge-MLP hidden width (W1 rows)
#define KP 256            // K padded 235 -> 256 for MFMA tiling
#define NB 3328           // H_DIM * ED_DIM = P column count

// P column layout: c = (d>>2)*256 + h*4 + (d&3)  [d4-major, h-interleaved]
// -> k_edge lane h reads 13 CONTIGUOUS uint2 blocks (512B/wave-instr).

// k_prep grid partition
#define BT_BLOCKS 940     // 235 i x 4 h-groups
#define EXT_BLOCKS 128
#define ZERO_BLOCKS 16
#define A_BLOCKS 1024     // A-build vectorized: 8 bf16 per thread
#define PREP_GRID (BT_BLOCKS + EXT_BLOCKS + ZERO_BLOCKS + A_BLOCKS)

#define GEMM_GRID 1728    // 64 m-tiles x 27 n-tiles (pad tile skipped), 8-divisible

typedef __bf16 bf16x8 __attribute__((ext_vector_type(8)));
typedef __bf16 bf16x4_t __attribute__((ext_vector_type(4)));
typedef float f32x4 __attribute__((ext_vector_type(4)));

// Native f32->bf16 cast: RNE (bit-identical to the old integer-trick f2bf for
// non-NaN input). Compiler fuses adjacent pairs into v_cvt_pk_bf16_f32
// (1 instr / 2 values) -- the manual bit-munging was ~4 VALU/value and
// unfusable (guide m240: scalar cast beats hand-written conversion).
static __device__ inline unsigned short bf16b(float f) {
    __bf16 h = (__bf16)f;
    return __builtin_bit_cast(unsigned short, h);
}

// ---------------------------------------------------------------------------
// K_PREP: fused pre-GEMM work, one dispatch:
//  blocks [0,940):      Bt live cols (edge-MLP compose, d4-major col order)
//  blocks [940,1068):   ext cols (root / composed bias bc)
//  blocks [1068,1084):  Bt pad-col zeroing (rows 0..3455, cols 235..255)
//  blocks [1084,2108):  A = bf16(x) zero-padded, 8 elts/thread, 16B stores
__global__ __launch_bounds__(256) void k_prep(const float* __restrict__ x,
                                              const float* __restrict__ W1,
                                              const float* __restrict__ W2,
                                              const float* __restrict__ b1,
                                              const float* __restrict__ b2,
                                              const float* __restrict__ root,
                                              unsigned short* __restrict__ A,
                                              unsigned short* __restrict__ Bt) {
    __shared__ float w1s[ED_DIM * 132];       // [d][k] padded
    __shared__ float w2s[16 * 132];           // [hh][k] padded
    const int bx = blockIdx.x;
    const int t = threadIdx.x;

    if (bx < BT_BLOCKS) {
        // C[i][(h,d)] = sum_k W2[(i*64+h)*128+k]*W1[k*52+d], stored at
        // Bt[p][i] with p = (d>>2)*256 + h*4 + (d&3).
        const int i = bx >> 2;                // 0..234
        const int by = bx & 3;                // h base by*16
        for (int j = t; j < ED_DIM * HID1; j += 256) {
            const int k = j / ED_DIM, d = j - k * ED_DIM;
            w1s[d * 132 + k] = W1[j];
        }
        const float* w2src = W2 + ((size_t)i * 64 + by * 16) * HID1;
        for (int j = t; j < 16 * HID1; j += 256) w2s[(j >> 7) * 132 + (j & 127)] = w2src[j];
        __syncthreads();
        const int hh = t & 15, dq = t >> 4;
        const int h = by * 16 + hh;
        const float4* w2v = (const float4*)&w2s[hh * 132];
        #pragma unroll
        for (int m = 0; m < 4; ++m) {
            const int d = dq + m * 16;
            if (d >= ED_DIM) break;
            const float4* w1v = (const float4*)&w1s[d * 132];
            float acc = 0.f;
            #pragma unroll
            for (int k4 = 0; k4 < HID1 / 4; ++k4) {
                const float4 a = w1v[k4], b = w2v[k4];
                acc += a.x * b.x + a.y * b.y + a.z * b.z + a.w * b.w;
            }
            const int p = ((d >> 2) << 8) + h * 4 + (d & 3);
            Bt[(size_t)p * KP + i] = bf16b(acc);
        }
    } else if (bx < BT_BLOCKS + EXT_BLOCKS) {
        // ext cols: 3328+j (j<64) = root[:,j]; 3392+j = bc[:,j-64]
        const int j = bx - BT_BLOCKS;         // 0..127
        const int i = t;                      // 0..255
        if (i < IN_DIM) {
            float v;
            if (j < 64) {
                v = root[i * H_DIM + j];
            } else {
                const int jj = i * H_DIM + (j - 64);
                float acc = b2[jj];
                const float4* w = (const float4*)(W2 + (size_t)jj * HID1);
                const float4* bv = (const float4*)b1;
                #pragma unroll
                for (int k4 = 0; k4 < HID1 / 4; ++k4) {
                    const float4 a = w[k4], b = bv[k4];
                    acc += a.x * b.x; acc += a.y * b.y; acc += a.z * b.z; acc += a.w * b.w;
                }
                v = acc;
            }
            Bt[(size_t)(NB + j) * KP + i] = bf16b(v);
        }
    } else if (bx < BT_BLOCKS + EXT_BLOCKS + ZERO_BLOCKS) {
        // Bt pad-col zeroing: rows 0..3455, cols 235..255 (rows 3456+ never read)
        const int z = bx - BT_BLOCKS - EXT_BLOCKS;
        const int TOT = 3456 * 21;
        for (int idx = z * 256 + t; idx < TOT; idx += ZERO_BLOCKS * 256) {
            const int r = idx / 21, c = IN_DIM + idx - r * 21;
            Bt[(size_t)r * KP + c] = 0;
        }
    } else {
        // A build: x (fp32) -> A (bf16 [8192,256], cols >=235 zero), 8/thread
        const int j8 = (bx - BT_BLOCKS - EXT_BLOCKS - ZERO_BLOCKS) * 256 + t;
        const int n = j8 >> 5, i0 = (j8 & 31) * 8;
        const float* xr = x + (size_t)n * IN_DIM;
        union { unsigned short us[8]; uint4 q; } pk;
        #pragma unroll
        for (int k = 0; k < 8; ++k) {
            const int i = i0 + k;
            pk.us[k] = (i < IN_DIM) ? bf16b(xr[i]) : (unsigned short)0;
        }
        *(uint4*)(&A[(size_t)j8 * 8]) = pk.q;
    }
}

// ---------------------------------------------------------------------------
// K2: [8192,256] x [256,3456] GEMM, 128x128 tile / BK=32 / 256 thr
// (4 waves, each 64x64 = 4x4 MFMA). ~3 blocks/CU resident.
// XCD-aware remap (1728 % 8 == 0), prefetch-after-barrier dbuf, XOR source
// swizzle (linear LDS dest for global_load_lds), swapped MFMA operands.
// n-tile 26 = ext tile: cols 3328..3391 -> agg(+conv_b), 3392..3455 -> xb2.
__global__ __launch_bounds__(256) void k_gemm(const unsigned short* __restrict__ A,
                                              const unsigned short* __restrict__ Bt,
                                              unsigned short* __restrict__ P,
                                              float* __restrict__ agg,
                                              float* __restrict__ xb2,
                                              const float* __restrict__ conv_b) {
    __shared__ unsigned short As[2 * 128 * 32];   // 16 KB dbuf
    __shared__ unsigned short Bs[2 * 128 * 32];   // 16 KB dbuf
    const int t = threadIdx.x;
    const int lin = blockIdx.x;                   // 0..1727
    const int xcd = lin & 7, bi = lin >> 3;       // 216 blocks per XCD
    const int mt = (bi / 27) * 8 + xcd;           // 0..63
    const int nt = bi % 27;                       // 0..26
    const int m0 = mt * 128, n0 = nt * 128;
    const int wid = t >> 6, lane = t & 63;
    const int wm = wid & 1;          // 0..1 : 64-row half
    const int wn = wid >> 1;         // 0..1 : 64-col half
    const int q = lane >> 4, r16 = lane & 15;

    f32x4 acc[4][4] = {};

    auto stage = [&](int k0, int buf) {
        #pragma unroll
        for (int s = 0; s < 2; ++s) {
            const int idx = s * 256 + t;          // 0..511, one 16B slot each
            const int row = idx >> 2;             // 0..127
            const int lgrp = ((idx & 3) ^ ((row >> 1) & 3)) * 8;  // logical k-chunk
            const unsigned short* ga = &A[(size_t)(m0 + row) * KP + k0 + lgrp];
            const unsigned short* gb = &Bt[(size_t)(n0 + row) * KP + k0 + lgrp];
            char* la = (char*)As + buf * 8192 + s * 4096 + wid * 1024;
            char* lb = (char*)Bs + buf * 8192 + s * 4096 + wid * 1024;
            __builtin_amdgcn_global_load_lds(
                (const __attribute__((address_space(1))) unsigned int*)ga,
                (__attribute__((address_space(3))) unsigned int*)la, 16, 0, 0);
            __builtin_amdgcn_global_load_lds(
                (const __attribute__((address_space(1))) unsigned int*)gb,
                (__attribute__((address_space(3))) unsigned int*)lb, 16, 0, 0);
        }
    };

    stage(0, 0);
    const int pcq = (q ^ ((r16 >> 1) & 3)) * 8;       // physical chunk for logical q
    #pragma unroll
    for (int it = 0; it < 8; ++it) {
        __syncthreads();                              // drains prefetch for buf[it&1]
        if (it < 7) stage((it + 1) * 32, (it + 1) & 1);
        const int bo = (it & 1) * 4096;               // buffer offset in shorts
        bf16x8 af[4], bfr[4];
        #pragma unroll
        for (int mi = 0; mi < 4; ++mi)
            af[mi] = *(const bf16x8*)(&As[bo + (wm * 64 + mi * 16 + r16) * 32 + pcq]);
        #pragma unroll
        for (int ni = 0; ni < 4; ++ni)
            bfr[ni] = *(const bf16x8*)(&Bs[bo + (wn * 64 + ni * 16 + r16) * 32 + pcq]);
        #pragma unroll
        for (int mi = 0; mi < 4; ++mi)
            #pragma unroll
            for (int ni = 0; ni < 4; ++ni)
                acc[mi][ni] = __builtin_amdgcn_mfma_f32_16x16x32_bf16(
                    bfr[ni], af[mi], acc[mi][ni], 0, 0, 0);   // transposed D
    }

    // Transposed D: lane (q,r16) holds rows m = mi*16+r16, cols n = ni*16+q*4..+3
    if (nt < 26) {
        #pragma unroll
        for (int mi = 0; mi < 4; ++mi)
            #pragma unroll
            for (int ni = 0; ni < 4; ++ni) {
                const int row = m0 + wm * 64 + mi * 16 + r16;
                const int col = n0 + wn * 64 + ni * 16 + q * 4;
                bf16x4_t pk;
                pk[0] = (__bf16)acc[mi][ni][0];
                pk[1] = (__bf16)acc[mi][ni][1];
                pk[2] = (__bf16)acc[mi][ni][2];
                pk[3] = (__bf16)acc[mi][ni][3];
                *(bf16x4_t*)(&P[(size_t)row * NB + col]) = pk;
            }
    } else {
        // ext tile: local col cl = ni*16 + q*4; wn==0 -> agg(+conv_b), else xb2
        #pragma unroll
        for (int mi = 0; mi < 4; ++mi)
            #pragma unroll
            for (int ni = 0; ni < 4; ++ni) {
                const int row = m0 + wm * 64 + mi * 16 + r16;
                const int cl = ni * 16 + q * 4;       // 0..63 within the half
                if (wn == 0) {
                    const float4 cb = *(const float4*)&conv_b[cl];
                    float4 v;
                    v.x = acc[mi][ni][0] + cb.x; v.y = acc[mi][ni][1] + cb.y;
                    v.z = acc[mi][ni][2] + cb.z; v.w = acc[mi][ni][3] + cb.w;
                    *(float4*)(&agg[row * H_DIM + cl]) = v;
                } else {
                    float4 v;
                    v.x = acc[mi][ni][0]; v.y = acc[mi][ni][1];
                    v.z = acc[mi][ni][2]; v.w = acc[mi][ni][3];
                    *(float4*)(&xb2[row * H_DIM + cl]) = v;
                }
            }
    }
}

// ---------------------------------------------------------------------------
// K4: per edge (one wave, lane=h). d4-major P: lane h's j-th uint2 sits at
// uint2 index j*64+h -> each of the 13 loads is 512B contiguous across the
// wave. eav[j] pairs with d=4j..4j+3 exactly as the h-major layout did.
__global__ __launch_bounds__(256) void k_edge(const int* __restrict__ ei,
                                              const float* __restrict__ ea,
                                              const unsigned short* __restrict__ P,
                                              const float* __restrict__ xb2,
                                              float* __restrict__ agg) {
    const int e = (blockIdx.x * 256 + threadIdx.x) >> 6;
    const int h = threadIdx.x & 63;
    if (e >= N_EDGES) return;
    const int s = ei[e], dst = ei[N_EDGES + e];
    const uint2* Pr = (const uint2*)(P + (size_t)s * NB);
    const float4* ev = (const float4*)(ea + (size_t)e * ED_DIM);

    uint2 pv[13];
    #pragma unroll
    for (int j = 0; j < 13; ++j) pv[j] = Pr[j * 64 + h];
    float4 eav[13];
    #pragma unroll
    for (int j = 0; j < 13; ++j) eav[j] = ev[j];

    float acc = xb2[s * H_DIM + h];
    #pragma unroll
    for (int j = 0; j < 13; ++j) {
        union { unsigned u; float f; } a0, a1, b0, b1;
        a0.u = pv[j].x << 16; a1.u = pv[j].x & 0xffff0000u;
        b0.u = pv[j].y << 16; b1.u = pv[j].y & 0xffff0000u;
        acc += eav[j].x * a0.f + eav[j].y * a1.f
             + eav[j].z * b0.f + eav[j].w * b1.f;
    }
    atomicAdd(&agg[dst * H_DIM + h], acc);
}

// ---------------------------------------------------------------------------
// K_TAIL: fused relu + mean-pool + MLP head, one block per graph.
// batch is SORTED -> per-graph node range via binary search; no atomics.
__global__ __launch_bounds__(256) void k_tail(const float* __restrict__ agg,
                                              const int* __restrict__ batch,
                                              const float* __restrict__ fw1, const float* __restrict__ fb1,
                                              const float* __restrict__ fw2, const float* __restrict__ fb2,
                                              const float* __restrict__ fw3, const float* __restrict__ fb3,
                                              const float* __restrict__ fw4, const float* __restrict__ fb4,
                                              float* __restrict__ out) {
    __shared__ __align__(16) float red[256];
    __shared__ __align__(16) float sp[64];
    __shared__ __align__(16) float s1[128];
    __shared__ __align__(16) float s2[256];
    __shared__ __align__(16) float s3[128];
    const int g = blockIdx.x, t = threadIdx.x;

    int lo = 0, hi = N_NODES;
    while (lo < hi) { const int mid = (lo + hi) >> 1; if (batch[mid] < g) lo = mid + 1; else hi = mid; }
    const int start = lo;
    hi = N_NODES;
    while (lo < hi) { const int mid = (lo + hi) >> 1; if (batch[mid] <= g) lo = mid + 1; else hi = mid; }
    const int end = lo;
    const float inv = 1.0f / fmaxf((float)(end - start), 1.0f);

    float a = 0.f;
    for (int n = start + (t >> 6); n < end; n += 4)
        a += fmaxf(agg[n * H_DIM + (t & 63)], 0.f);
    red[t] = a;
    __syncthreads();
    if (t < 64) sp[t] = (red[t] + red[t + 64] + red[t + 128] + red[t + 192]) * inv;
    __syncthreads();

    if (t < 128) {
        float acc = fb1[t];
        const float4* w = (const float4*)(fw1 + t * 64);
        const float4* sv = (const float4*)sp;
        #pragma unroll
        for (int k = 0; k < 16; ++k) {
            const float4 a4 = w[k], b4 = sv[k];
            acc += a4.x * b4.x; acc += a4.y * b4.y; acc += a4.z * b4.z; acc += a4.w * b4.w;
        }
        s1[t] = fmaxf(acc, 0.f);
    }
    __syncthreads();
    {
        float acc = fb2[t];
        const float4* w = (const float4*)(fw2 + t * 128);
        const float4* sv = (const float4*)s1;
        #pragma unroll
        for (int k = 0; k < 32; ++k) {
            const float4 a4 = w[k], b4 = sv[k];
            acc += a4.x * b4.x; acc += a4.y * b4.y; acc += a4.z * b4.z; acc += a4.w * b4.w;
        }
        s2[t] = fmaxf(acc, 0.f);
    }
    __syncthreads();
    if (t < 128) {
        float acc = fb3[t];
        const float4* w = (const float4*)(fw3 + t * 256);
        const float4* sv = (const float4*)s2;
        #pragma unroll
        for (int k = 0; k < 64; ++k) {
            const float4 a4 = w[k], b4 = sv[k];
            acc += a4.x * b4.x; acc += a4.y * b4.y; acc += a4.z * b4.z; acc += a4.w * b4.w;
        }
        s3[t] = fmaxf(acc, 0.f);
    }
    __syncthreads();
    if (t < 64) {
        float p = s3[t] * fw4[t] + s3[t + 64] * fw4[t + 64];
        #pragma unroll
        for (int off = 32; off > 0; off >>= 1) p += __shfl_down(p, off);
        if (t == 0) out[g] = p + fb4[0];
    }
}

// ---------------------------------------------------------------------------
extern "C" void kernel_launch(void* const* d_in, const int* in_sizes, int n_in,
                              void* d_out, int out_size, void* d_ws, size_t ws_size,
                              hipStream_t stream) {
    const float* x      = (const float*)d_in[0];
    const int*   ei     = (const int*)d_in[1];
    const float* ea     = (const float*)d_in[2];
    const int*   batch  = (const int*)d_in[3];
    const float* W1     = (const float*)d_in[4];
    const float* b1     = (const float*)d_in[5];
    const float* W2     = (const float*)d_in[6];
    const float* b2     = (const float*)d_in[7];
    const float* root   = (const float*)d_in[8];
    const float* conv_b = (const float*)d_in[9];
    const float* fw1 = (const float*)d_in[10]; const float* fb1 = (const float*)d_in[11];
    const float* fw2 = (const float*)d_in[12]; const float* fb2 = (const float*)d_in[13];
    const float* fw3 = (const float*)d_in[14]; const float* fb3 = (const float*)d_in[15];
    const float* fw4 = (const float*)d_in[16]; const float* fb4 = (const float*)d_in[17];
    float* out = (float*)d_out;

    char* ws = (char*)d_ws;
    // workspace layout (16B-aligned), total ~64.8 MB
    unsigned short* A   = (unsigned short*)(ws);             // 8192*256*2   = 4,194,304
    unsigned short* Bt  = (unsigned short*)(ws + 4194304);   // 3584*256*2   = 1,835,008
    unsigned short* P   = (unsigned short*)(ws + 6029312);   // 8192*3328*2  = 54,525,952
    float* agg  = (float*)(ws + 60555264);                   // 8192*64*4    = 2,097,152
    float* xb2  = (float*)(ws + 62652416);                   // 8192*64*4    = 2,097,152

    k_prep<<<dim3(PREP_GRID), dim3(256), 0, stream>>>(x, W1, W2, b1, b2, root, A, Bt);
    k_gemm<<<dim3(GEMM_GRID), dim3(256), 0, stream>>>(A, Bt, P, agg, xb2, conv_b);
    k_edge<<<dim3(N_EDGES / 4), dim3(256), 0, stream>>>(ei, ea, P, xb2, agg);
    k_tail<<<dim3(N_GRAPHS), dim3(256), 0, stream>>>(agg, batch, fw1, fb1, fw2, fb2, fw3, fb3, fw4, fb4, out);
}